// Round 8
// baseline (357.007 us; speedup 1.0000x reference)
//
#include <hip/hip_runtime.h>

typedef unsigned short ushort;
typedef unsigned int uint;
typedef __bf16 bf16x8 __attribute__((ext_vector_type(8)));
typedef float floatx4 __attribute__((ext_vector_type(4)));
typedef ushort ushort8 __attribute__((ext_vector_type(8)));

constexpr int LQ = 5440;
constexpr int ROWS = 43520;   // batch(8) * 5440

__device__ __forceinline__ ushort f2b(float f) {
  union { float f; uint i; } v; v.f = f;
  uint r = v.i + 0x7FFFu + ((v.i >> 16) & 1u);
  return (ushort)(r >> 16);
}
__device__ __forceinline__ float blo(uint u) {
  union { uint i; float f; } v; v.i = u << 16; return v.f;
}
__device__ __forceinline__ float bhi(uint u) {
  union { uint i; float f; } v; v.i = u & 0xFFFF0000u; return v.f;
}
// async global->LDS, 16B per lane; LDS dest must be uniform_base + lane*16
__device__ __forceinline__ void glds16(const ushort* g, ushort* l) {
  __builtin_amdgcn_global_load_lds(
      (const __attribute__((address_space(1))) void*)g,
      (__attribute__((address_space(3))) void*)l, 16, 0, 0);
}

// ---------------- weight transpose + cast: Wt[n][k] bf16 ----------------
// layout: [0]=Wval(256r) [65536]=Woff(256r)+Wattn(128r) fused 384-row block [163840]=Wout(256r)
__global__ __launch_bounds__(256) void wcast_kernel(
    const float* __restrict__ Wv, const float* __restrict__ Wo,
    const float* __restrict__ Wa, const float* __restrict__ Wu,
    ushort* __restrict__ Wt) {
  int k = threadIdx.x;    // 0..255
  int n = blockIdx.x;     // 0..255
  int m = blockIdx.y;     // 0..3
  const float* src = (m == 0) ? Wv : (m == 1) ? Wo : (m == 2) ? Wa : Wu;
  int N = (m == 2) ? 128 : 256;
  if (n >= N) return;
  size_t off = (size_t)m * 65536 - ((m == 3) ? 32768 : 0);  // 0,65536,131072,163840
  Wt[off + (size_t)n * 256 + k] = f2b(src[(size_t)k * N + n]);
}

// ---------------- qcast: query fp32 -> bf16 (enables glds16 A-path in oa) --------
__global__ __launch_bounds__(256) void qcast_kernel(
    const float* __restrict__ Q, ushort* __restrict__ Qb) {
  int u = blockIdx.x * 256 + threadIdx.x;      // 5440*256 = 1,392,640 x 8 elems
  const float4* s = (const float4*)Q + (size_t)u * 2;
  float4 a0 = s[0], a1 = s[1];
  ushort8 o;
  o[0] = f2b(a0.x); o[1] = f2b(a0.y); o[2] = f2b(a0.z); o[3] = f2b(a0.w);
  o[4] = f2b(a1.x); o[5] = f2b(a1.y); o[6] = f2b(a1.z); o[7] = f2b(a1.w);
  *(ushort8*)(Qb + (size_t)u * 8) = o;
}

// ---------------- K1: value GEMM, 32x256 tile (1360 blocks), B via glds16 --------
__global__ __launch_bounds__(256) void gemm_val64(
    const float* __restrict__ X, const ushort* __restrict__ WtV,
    const float* __restrict__ bval, ushort* __restrict__ value16) {
  __shared__ ushort At[1024];    // 32r x 32k, MFMA order
  __shared__ ushort Bs[8192];    // 256n x 32k, MFMA order
  const int t = threadIdx.x, lane = t & 63, wv = t >> 6;
  const int row_base = blockIdx.x * 32;
  floatx4 acc[2][4];
#pragma unroll
  for (int i = 0; i < 2; ++i)
#pragma unroll
    for (int j = 0; j < 4; ++j) acc[i][j] = floatx4{0.f, 0.f, 0.f, 0.f};

  // A staging (t<128): fp32 -> f2b, MFMA order
  const float* ap = nullptr;
  ushort* aslot = nullptr;
  if (t < 128) {
    int r = t >> 2, q = t & 3;         // r 0..31
    ap = X + (size_t)(row_base + r) * 256 + q * 8;
    aslot = &At[((r >> 4) * 64 + q * 16 + (r & 15)) * 8];
  }
  const ushort* bsrc[4];
#pragma unroll
  for (int i = 0; i < 4; ++i) {
    int l = t + 256 * i;                      // 0..1023 16B-units
    int nt = l >> 6, qq = (l >> 4) & 3, n15 = l & 15;
    bsrc[i] = WtV + (size_t)(nt * 16 + n15) * 256 + qq * 8;
  }

  for (int k0 = 0; k0 < 256; k0 += 32) {
#pragma unroll
    for (int i = 0; i < 4; ++i) glds16(bsrc[i] + k0, &Bs[(t + 256 * i) * 8]);
    if (t < 128) {
      float4 a0 = *(const float4*)(ap + k0), a1 = *(const float4*)(ap + k0 + 4);
      ushort8 u;
      u[0] = f2b(a0.x); u[1] = f2b(a0.y); u[2] = f2b(a0.z); u[3] = f2b(a0.w);
      u[4] = f2b(a1.x); u[5] = f2b(a1.y); u[6] = f2b(a1.z); u[7] = f2b(a1.w);
      *(ushort8*)aslot = u;
    }
    __syncthreads();
    bf16x8 af[2], bf[4];
#pragma unroll
    for (int ti = 0; ti < 2; ++ti)
      af[ti] = *(const bf16x8*)&At[(ti * 64 + lane) * 8];
#pragma unroll
    for (int tj = 0; tj < 4; ++tj)
      bf[tj] = *(const bf16x8*)&Bs[((4 * wv + tj) * 64 + lane) * 8];
#pragma unroll
    for (int ti = 0; ti < 2; ++ti)
#pragma unroll
      for (int tj = 0; tj < 4; ++tj)
        acc[ti][tj] = __builtin_amdgcn_mfma_f32_16x16x32_bf16(af[ti], bf[tj], acc[ti][tj], 0, 0, 0);
    __syncthreads();
  }
  const int quad = lane >> 4, l15 = lane & 15;
#pragma unroll
  for (int tj = 0; tj < 4; ++tj) {
    int gcol = (4 * wv + tj) * 16 + l15;
    float b = bval[gcol];
#pragma unroll
    for (int ti = 0; ti < 2; ++ti)
#pragma unroll
      for (int reg = 0; reg < 4; ++reg) {
        int grow = row_base + ti * 16 + quad * 4 + reg;
        value16[(size_t)grow * 256 + gcol] = f2b(acc[ti][tj][reg] + b);
      }
  }
}

// ---------------- K2: off+attn GEMM (A bf16 via glds16) + softmax (no max-sub) ----
// slot = {i00|i01<<16, i10|i11<<16, w00|w01, w10|w11} (bf16*aw)  [round-0 format]
__global__ __launch_bounds__(256) void gemm_oa_kernel(
    const ushort* __restrict__ Qb, const ushort* __restrict__ WtOA,
    const float* __restrict__ boff, const float* __restrict__ battn,
    const float* __restrict__ refp, uint4* __restrict__ tblq) {
  __shared__ ushort At[2048];
  __shared__ ushort Bs[3072];
  const int t = threadIdx.x;
  const int lane = t & 63, wv = t >> 6;
  const int quad = lane >> 4, l15 = lane & 15;
  const int bx = blockIdx.x;
  const int row_base = (bx % 680) * 64;
  const int hp = bx / 680;            // 0..3
  floatx4 accO[4], accA[2];
#pragma unroll
  for (int p = 0; p < 4; ++p) accO[p] = floatx4{0.f, 0.f, 0.f, 0.f};
#pragma unroll
  for (int q = 0; q < 2; ++q) accA[q] = floatx4{0.f, 0.f, 0.f, 0.f};

  // A source (bf16, pre-swizzled to MFMA order), 1 glds16/thread/k-step
  const ushort* asrc;
  {
    int rt = t >> 6, qq = (t >> 4) & 3, r15 = t & 15;
    asrc = Qb + (size_t)(row_base + rt * 16 + r15) * 256 + qq * 8;
  }
  const ushort* osrc0;
  const ushort* osrc1 = nullptr;
  {
    int nt = t >> 6, qq = (t >> 4) & 3, n15 = t & 15;
    int nr = nt * 16 + n15;
    int grow_ = (nr < 64) ? (hp * 64 + nr) : (256 + hp * 32 + (nr - 64));
    osrc0 = WtOA + (size_t)grow_ * 256 + qq * 8;
  }
  if (t < 128) {
    int l = t + 256;
    int nt = l >> 6, qq = (l >> 4) & 3, n15 = l & 15;
    int nr = nt * 16 + n15;                  // 64..95
    int grow_ = 256 + hp * 32 + (nr - 64);
    osrc1 = WtOA + (size_t)grow_ * 256 + qq * 8;
  }

  for (int k0 = 0; k0 < 256; k0 += 32) {
    glds16(asrc + k0, &At[t * 8]);
    glds16(osrc0 + k0, &Bs[t * 8]);
    if (t < 128) glds16(osrc1 + k0, &Bs[(t + 256) * 8]);
    __syncthreads();
    bf16x8 af = *(const bf16x8*)&At[(wv * 64 + lane) * 8];
#pragma unroll
    for (int p = 0; p < 4; ++p) {
      bf16x8 bf = *(const bf16x8*)&Bs[(p * 64 + lane) * 8];
      accO[p] = __builtin_amdgcn_mfma_f32_16x16x32_bf16(af, bf, accO[p], 0, 0, 0);
    }
#pragma unroll
    for (int qk = 0; qk < 2; ++qk) {
      bf16x8 bf = *(const bf16x8*)&Bs[((4 + qk) * 64 + lane) * 8];
      accA[qk] = __builtin_amdgcn_mfma_f32_16x16x32_bf16(af, bf, accA[qk], 0, 0, 0);
    }
    __syncthreads();
  }

  // epilogue: per-thread 8 slot-units (4 reg x 2 heads)
  const int lp = l15, l = lp >> 2;
  const int wd = 64 >> l;
  const int st = (l == 0) ? 0 : (l == 1) ? 4096 : (l == 2) ? 5120 : 5376;
  const float lw = (float)wd;
  const int src = (quad << 4) | (2 * (lp & 7));
  float boO[4], boA[2];
#pragma unroll
  for (int p = 0; p < 4; ++p) boO[p] = boff[(4 * hp + p) * 16 + l15];
#pragma unroll
  for (int qk = 0; qk < 2; ++qk) boA[qk] = battn[(2 * hp + qk) * 16 + l15];

#pragma unroll
  for (int reg = 0; reg < 4; ++reg) {
    int grow = row_base + wv * 16 + quad * 4 + reg;
    float rx = refp[(size_t)grow * 8 + l * 2];
    float ry = refp[(size_t)grow * 8 + l * 2 + 1];
#pragma unroll
    for (int hh = 0; hh < 2; ++hh) {
      int h = 2 * hp + hh;
      // softmax without max-subtraction: logits ~ N(0,1), exp safe in fp32
      float xa = accA[hh][reg] + boA[hh];
      float e = __expf(xa);
      float ssum = e;
      ssum += __shfl_xor(ssum, 1, 64);
      ssum += __shfl_xor(ssum, 2, 64);
      ssum += __shfl_xor(ssum, 4, 64);
      ssum += __shfl_xor(ssum, 8, 64);
      float aw = e / ssum;
      float v0 = accO[2 * hh][reg] + boO[2 * hh];
      float v1 = accO[2 * hh + 1][reg] + boO[2 * hh + 1];
      float x_lo = __shfl(v0, src, 64),     x_hi = __shfl(v1, src, 64);
      float y_lo = __shfl(v0, src | 1, 64), y_hi = __shfl(v1, src | 1, 64);
      float xo = (lp < 8) ? x_lo : x_hi;
      float yo = (lp < 8) ? y_lo : y_hi;
      float X = rx * lw + xo - 0.5f;     // == (ref + off/W)*W - 0.5
      float Y = ry * lw + yo - 0.5f;
      float fx = floorf(X), fy = floorf(Y);
      float lx = X - fx, ly = Y - fy;
      int x0 = (int)fx, y0 = (int)fy, x1 = x0 + 1, y1 = y0 + 1;
      int cx0 = min(max(x0, 0), wd - 1), cx1 = min(max(x1, 0), wd - 1);
      int cy0 = min(max(y0, 0), wd - 1), cy1 = min(max(y1, 0), wd - 1);
      float vx0 = (x0 >= 0 && x0 < wd) ? 1.f : 0.f;
      float vx1 = (x1 >= 0 && x1 < wd) ? 1.f : 0.f;
      float vy0 = (y0 >= 0 && y0 < wd) ? 1.f : 0.f;
      float vy1 = (y1 >= 0 && y1 < wd) ? 1.f : 0.f;
      float g00 = (1.f - lx) * (1.f - ly) * vx0 * vy0 * aw;
      float g01 = lx * (1.f - ly) * vx1 * vy0 * aw;
      float g10 = (1.f - lx) * ly * vx0 * vy1 * aw;
      float g11 = lx * ly * vx1 * vy1 * aw;
      uint i00 = st + cy0 * wd + cx0, i01 = st + cy0 * wd + cx1;
      uint i10 = st + cy1 * wd + cx0, i11 = st + cy1 * wd + cx1;
      uint4 ov;
      ov.x = i00 | (i01 << 16);
      ov.y = i10 | (i11 << 16);
      ov.z = (uint)f2b(g00) | ((uint)f2b(g01) << 16);
      ov.w = (uint)f2b(g10) | ((uint)f2b(g11) << 16);
      tblq[((size_t)grow * 8 + h) * 16 + lp] = ov;
    }
  }
}

// ---------------- K3: bilinear core, 2 rows per wave (round-0 best: 120.8us) ------
__global__ __launch_bounds__(512) void core_kernel(
    const ushort* __restrict__ value16, const uint4* __restrict__ tblq,
    uint* __restrict__ coreo32) {
  const int bx = blockIdx.x;           // 21760
  const int b = bx & 7;                // XCD-affine batch slice
  const int pr = bx >> 3;              // 0..2719
  const int brow0 = b * LQ + pr * 2;
  const int t = threadIdx.x;
  const int h = t >> 6, lane = t & 63;
  const int s = lane >> 3, g = lane & 7;
  const size_t sb = ((size_t)brow0 * 8 + h) * 16;
  uint4 sA0 = tblq[sb + s];
  uint4 sA1 = tblq[sb + 8 + s];
  uint4 sB0 = tblq[sb + 128 + s];
  uint4 sB1 = tblq[sb + 136 + s];
  const uint2* vb = (const uint2*)value16 + (size_t)b * (LQ * 64) + h * 8 + g;
  float a[4] = {0.f, 0.f, 0.f, 0.f};
  float c[4] = {0.f, 0.f, 0.f, 0.f};

  auto proc = [&](const uint4& sl, float* ac) {
    uint2 v00 = vb[(size_t)(sl.x & 0xFFFFu) * 64];
    uint2 v01 = vb[(size_t)(sl.x >> 16) * 64];
    uint2 v10 = vb[(size_t)(sl.y & 0xFFFFu) * 64];
    uint2 v11 = vb[(size_t)(sl.y >> 16) * 64];
    float w00 = blo(sl.z), w01 = bhi(sl.z), w10 = blo(sl.w), w11 = bhi(sl.w);
    ac[0] = fmaf(w00, blo(v00.x), ac[0]); ac[1] = fmaf(w00, bhi(v00.x), ac[1]);
    ac[2] = fmaf(w00, blo(v00.y), ac[2]); ac[3] = fmaf(w00, bhi(v00.y), ac[3]);
    ac[0] = fmaf(w01, blo(v01.x), ac[0]); ac[1] = fmaf(w01, bhi(v01.x), ac[1]);
    ac[2] = fmaf(w01, blo(v01.y), ac[2]); ac[3] = fmaf(w01, bhi(v01.y), ac[3]);
    ac[0] = fmaf(w10, blo(v10.x), ac[0]); ac[1] = fmaf(w10, bhi(v10.x), ac[1]);
    ac[2] = fmaf(w10, blo(v10.y), ac[2]); ac[3] = fmaf(w10, bhi(v10.y), ac[3]);
    ac[0] = fmaf(w11, blo(v11.x), ac[0]); ac[1] = fmaf(w11, bhi(v11.x), ac[1]);
    ac[2] = fmaf(w11, blo(v11.y), ac[2]); ac[3] = fmaf(w11, bhi(v11.y), ac[3]);
  };
  proc(sA0, a); proc(sA1, a);
  proc(sB0, c); proc(sB1, c);

#pragma unroll
  for (int m = 8; m <= 32; m <<= 1) {
#pragma unroll
    for (int i = 0; i < 4; ++i) {
      a[i] += __shfl_xor(a[i], m, 64);
      c[i] += __shfl_xor(c[i], m, 64);
    }
  }
  if (s == 0) {
    uint2 o0, o1;
    o0.x = (uint)f2b(a[0]) | ((uint)f2b(a[1]) << 16);
    o0.y = (uint)f2b(a[2]) | ((uint)f2b(a[3]) << 16);
    o1.x = (uint)f2b(c[0]) | ((uint)f2b(c[1]) << 16);
    o1.y = (uint)f2b(c[2]) | ((uint)f2b(c[3]) << 16);
    *(uint2*)(coreo32 + (size_t)brow0 * 128 + h * 16 + g * 2) = o0;
    *(uint2*)(coreo32 + (size_t)(brow0 + 1) * 128 + h * 16 + g * 2) = o1;
  }
}

// ---------------- K4: out GEMM, 32x256 tile (1360 blocks), A+B via glds16 --------
__global__ __launch_bounds__(256) void gemm_out64(
    const ushort* __restrict__ C, const ushort* __restrict__ WtU,
    const float* __restrict__ bout, float* __restrict__ out) {
  __shared__ ushort At[1024];
  __shared__ ushort Bs[8192];
  const int t = threadIdx.x, lane = t & 63, wv = t >> 6;
  const int row_base = blockIdx.x * 32;
  floatx4 acc[2][4];
#pragma unroll
  for (int i = 0; i < 2; ++i)
#pragma unroll
    for (int j = 0; j < 4; ++j) acc[i][j] = floatx4{0.f, 0.f, 0.f, 0.f};

  const ushort* asrc = nullptr;
  if (t < 128) {
    int rt = t >> 6, qq = (t >> 4) & 3, r15 = t & 15;
    asrc = C + (size_t)(row_base + rt * 16 + r15) * 256 + qq * 8;
  }
  const ushort* bsrc[4];
#pragma unroll
  for (int i = 0; i < 4; ++i) {
    int l = t + 256 * i;
    int nt = l >> 6, qq = (l >> 4) & 3, n15 = l & 15;
    bsrc[i] = WtU + (size_t)(nt * 16 + n15) * 256 + qq * 8;
  }

  for (int k0 = 0; k0 < 256; k0 += 32) {
    if (t < 128) glds16(asrc + k0, &At[t * 8]);
#pragma unroll
    for (int i = 0; i < 4; ++i) glds16(bsrc[i] + k0, &Bs[(t + 256 * i) * 8]);
    __syncthreads();
    bf16x8 af[2], bf[4];
#pragma unroll
    for (int ti = 0; ti < 2; ++ti)
      af[ti] = *(const bf16x8*)&At[(ti * 64 + lane) * 8];
#pragma unroll
    for (int tj = 0; tj < 4; ++tj)
      bf[tj] = *(const bf16x8*)&Bs[((4 * wv + tj) * 64 + lane) * 8];
#pragma unroll
    for (int ti = 0; ti < 2; ++ti)
#pragma unroll
      for (int tj = 0; tj < 4; ++tj)
        acc[ti][tj] = __builtin_amdgcn_mfma_f32_16x16x32_bf16(af[ti], bf[tj], acc[ti][tj], 0, 0, 0);
    __syncthreads();
  }
  const int quad = lane >> 4, l15 = lane & 15;
#pragma unroll
  for (int tj = 0; tj < 4; ++tj) {
    int gcol = (4 * wv + tj) * 16 + l15;
    float b = bout[gcol];
#pragma unroll
    for (int ti = 0; ti < 2; ++ti)
#pragma unroll
      for (int reg = 0; reg < 4; ++reg) {
        int grow = row_base + ti * 16 + quad * 4 + reg;
        out[(size_t)grow * 256 + gcol] = acc[ti][tj][reg] + b;
      }
  }
}

extern "C" void kernel_launch(void* const* d_in, const int* in_sizes, int n_in,
                              void* d_out, int out_size, void* d_ws, size_t ws_size,
                              hipStream_t stream) {
  const float* query  = (const float*)d_in[0];
  const float* refp   = (const float*)d_in[1];
  const float* inpf   = (const float*)d_in[2];
  const float* W_val  = (const float*)d_in[5];
  const float* b_val  = (const float*)d_in[6];
  const float* W_off  = (const float*)d_in[7];
  const float* b_off  = (const float*)d_in[8];
  const float* W_attn = (const float*)d_in[9];
  const float* b_attn = (const float*)d_in[10];
  const float* W_out  = (const float*)d_in[11];
  const float* b_out  = (const float*)d_in[12];

  char* ws = (char*)d_ws;
  ushort* Wt    = (ushort*)ws;                        // 458,752 B used (1 MB reserved)
  ushort* Qb    = (ushort*)(ws + 1048576);            // 22,282,240 B (bf16 query)
                                                      //   later ALIASED as coreo
  ushort* value = (ushort*)(ws + 23330816);           // 22,282,240 B (bf16, row-major)
  uint4*  tbl   = (uint4*)(ws + 45613056);            // 89,128,960 B (16 B slots)
  ushort* coreo = Qb;                                 // alias: Qb dead after oa
  // peak = 134,742,016 B

  dim3 blk(256);
  wcast_kernel<<<dim3(256, 4), blk, 0, stream>>>(W_val, W_off, W_attn, W_out, Wt);
  qcast_kernel<<<dim3(5440), blk, 0, stream>>>(query, Qb);
  gemm_val64  <<<dim3(1360), blk, 0, stream>>>(inpf, Wt, b_val, value);
  gemm_oa_kernel<<<dim3(2720), blk, 0, stream>>>(Qb, Wt + 65536, b_off, b_attn, refp, tbl);
  core_kernel <<<dim3(21760), dim3(512), 0, stream>>>(value, tbl, (uint*)coreo);
  gemm_out64  <<<dim3(1360), blk, 0, stream>>>(coreo, Wt + 163840, b_out, (float*)d_out);
}

// Round 9
// 349.766 us; speedup vs baseline: 1.0207x; 1.0207x over previous
//
#include <hip/hip_runtime.h>

typedef unsigned short ushort;
typedef unsigned int uint;
typedef __bf16 bf16x8 __attribute__((ext_vector_type(8)));
typedef float floatx4 __attribute__((ext_vector_type(4)));
typedef ushort ushort8 __attribute__((ext_vector_type(8)));

constexpr int LQ = 5440;
constexpr int ROWS = 43520;   // batch(8) * 5440

__device__ __forceinline__ ushort f2b(float f) {
  union { float f; uint i; } v; v.f = f;
  uint r = v.i + 0x7FFFu + ((v.i >> 16) & 1u);
  return (ushort)(r >> 16);
}
__device__ __forceinline__ float blo(uint u) {
  union { uint i; float f; } v; v.i = u << 16; return v.f;
}
__device__ __forceinline__ float bhi(uint u) {
  union { uint i; float f; } v; v.i = u & 0xFFFF0000u; return v.f;
}
// async global->LDS, 16B per lane; LDS dest must be uniform_base + lane*16
__device__ __forceinline__ void glds16(const ushort* g, ushort* l) {
  __builtin_amdgcn_global_load_lds(
      (const __attribute__((address_space(1))) void*)g,
      (__attribute__((address_space(3))) void*)l, 16, 0, 0);
}

// ---------------- weight transpose + cast: Wt[n][k] bf16 ----------------
// layout: [0]=Wval(256r) [65536]=Woff(256r)+Wattn(128r) fused 384-row block [163840]=Wout(256r)
__global__ __launch_bounds__(256) void wcast_kernel(
    const float* __restrict__ Wv, const float* __restrict__ Wo,
    const float* __restrict__ Wa, const float* __restrict__ Wu,
    ushort* __restrict__ Wt) {
  int k = threadIdx.x;    // 0..255
  int n = blockIdx.x;     // 0..255
  int m = blockIdx.y;     // 0..3
  const float* src = (m == 0) ? Wv : (m == 1) ? Wo : (m == 2) ? Wa : Wu;
  int N = (m == 2) ? 128 : 256;
  if (n >= N) return;
  size_t off = (size_t)m * 65536 - ((m == 3) ? 32768 : 0);  // 0,65536,131072,163840
  Wt[off + (size_t)n * 256 + k] = f2b(src[(size_t)k * N + n]);
}

// ---------------- K1: value GEMM, 64x256 full-N tile, B via global_load_lds ----------
// (R3 best version; A fp32 read once, f2b fused in staging)
__global__ __launch_bounds__(256) void gemm_val64(
    const float* __restrict__ X, const ushort* __restrict__ WtV,
    const float* __restrict__ bval, ushort* __restrict__ value16) {
  __shared__ ushort At[2048];    // 64r x 32k, MFMA order
  __shared__ ushort Bs[8192];    // 256n x 32k, MFMA order
  const int t = threadIdx.x, lane = t & 63, wv = t >> 6;
  const int row_base = blockIdx.x * 64;
  floatx4 acc[4][4];
#pragma unroll
  for (int i = 0; i < 4; ++i)
#pragma unroll
    for (int j = 0; j < 4; ++j) acc[i][j] = floatx4{0.f, 0.f, 0.f, 0.f};

  const int r = t >> 2, q = t & 3;
  const float* ap = X + (size_t)(row_base + r) * 256 + q * 8;
  ushort* aslot = &At[((r >> 4) * 64 + q * 16 + (r & 15)) * 8];
  const ushort* bsrc[4];
#pragma unroll
  for (int i = 0; i < 4; ++i) {
    int l = t + 256 * i;                      // 0..1023 16B-units
    int nt = l >> 6, qq = (l >> 4) & 3, n15 = l & 15;
    bsrc[i] = WtV + (size_t)(nt * 16 + n15) * 256 + qq * 8;
  }

  for (int k0 = 0; k0 < 256; k0 += 32) {
#pragma unroll
    for (int i = 0; i < 4; ++i) glds16(bsrc[i] + k0, &Bs[(t + 256 * i) * 8]);
    {
      float4 a0 = *(const float4*)(ap + k0), a1 = *(const float4*)(ap + k0 + 4);
      ushort8 u;
      u[0] = f2b(a0.x); u[1] = f2b(a0.y); u[2] = f2b(a0.z); u[3] = f2b(a0.w);
      u[4] = f2b(a1.x); u[5] = f2b(a1.y); u[6] = f2b(a1.z); u[7] = f2b(a1.w);
      *(ushort8*)aslot = u;
    }
    __syncthreads();
    bf16x8 af[4], bf[4];
#pragma unroll
    for (int ti = 0; ti < 4; ++ti)
      af[ti] = *(const bf16x8*)&At[(ti * 64 + lane) * 8];
#pragma unroll
    for (int tj = 0; tj < 4; ++tj)
      bf[tj] = *(const bf16x8*)&Bs[((4 * wv + tj) * 64 + lane) * 8];
#pragma unroll
    for (int ti = 0; ti < 4; ++ti)
#pragma unroll
      for (int tj = 0; tj < 4; ++tj)
        acc[ti][tj] = __builtin_amdgcn_mfma_f32_16x16x32_bf16(af[ti], bf[tj], acc[ti][tj], 0, 0, 0);
    __syncthreads();
  }
  const int quad = lane >> 4, l15 = lane & 15;
#pragma unroll
  for (int tj = 0; tj < 4; ++tj) {
    int gcol = (4 * wv + tj) * 16 + l15;
    float b = bval[gcol];
#pragma unroll
    for (int ti = 0; ti < 4; ++ti)
#pragma unroll
      for (int reg = 0; reg < 4; ++reg) {
        int grow = row_base + ti * 16 + quad * 4 + reg;
        value16[(size_t)grow * 256 + gcol] = f2b(acc[ti][tj][reg] + b);
      }
  }
}

// ---------------- K2: off+attn GEMM, MERGED heads (Q read once) ----------------
// 680 blocks x 64 rows; B = full 384 rows (24KB/k-step). Wave wv owns m-tile wv,
// all 24 n-tiles: accO[16] (off, 256c) + accA[8] (attn, 128c). 24 MFMA/wave/barrier.
// Epilogue identical math/order to R3 (heads h=0..7 per thread).
__global__ __launch_bounds__(256) void gemm_oa_kernel(
    const float* __restrict__ Q, const ushort* __restrict__ WtOA,
    const float* __restrict__ boff, const float* __restrict__ battn,
    const float* __restrict__ refp, uint4* __restrict__ tblq) {
  __shared__ ushort At[2048];     // 64r x 32k
  __shared__ ushort Bs[12288];    // 384r x 32k
  const int t = threadIdx.x;
  const int lane = t & 63, wv = t >> 6;
  const int quad = lane >> 4, l15 = lane & 15;
  const int row_base = blockIdx.x * 64;
  floatx4 accO[16], accA[8];
#pragma unroll
  for (int p = 0; p < 16; ++p) accO[p] = floatx4{0.f, 0.f, 0.f, 0.f};
#pragma unroll
  for (int qk = 0; qk < 8; ++qk) accA[qk] = floatx4{0.f, 0.f, 0.f, 0.f};

  const int r = t >> 2, q = t & 3;
  const float* ap = Q + (size_t)(row_base + r) * 256 + q * 8;
  ushort* aslot = &At[((r >> 4) * 64 + q * 16 + (r & 15)) * 8];
  const ushort* bsrc[6];
#pragma unroll
  for (int i = 0; i < 6; ++i) {
    int l = t + 256 * i;                      // 0..1535 16B-units
    int nt = l >> 6, qq = (l >> 4) & 3, n15 = l & 15;
    bsrc[i] = WtOA + (size_t)(nt * 16 + n15) * 256 + qq * 8;
  }

  for (int k0 = 0; k0 < 256; k0 += 32) {
#pragma unroll
    for (int i = 0; i < 6; ++i) glds16(bsrc[i] + k0, &Bs[(t + 256 * i) * 8]);
    {
      float4 a0 = *(const float4*)(ap + k0), a1 = *(const float4*)(ap + k0 + 4);
      ushort8 u;
      u[0] = f2b(a0.x); u[1] = f2b(a0.y); u[2] = f2b(a0.z); u[3] = f2b(a0.w);
      u[4] = f2b(a1.x); u[5] = f2b(a1.y); u[6] = f2b(a1.z); u[7] = f2b(a1.w);
      *(ushort8*)aslot = u;
    }
    __syncthreads();
    bf16x8 af = *(const bf16x8*)&At[(wv * 64 + lane) * 8];
#pragma unroll
    for (int p = 0; p < 16; ++p) {
      bf16x8 bf = *(const bf16x8*)&Bs[(p * 64 + lane) * 8];
      accO[p] = __builtin_amdgcn_mfma_f32_16x16x32_bf16(af, bf, accO[p], 0, 0, 0);
    }
#pragma unroll
    for (int qk = 0; qk < 8; ++qk) {
      bf16x8 bf = *(const bf16x8*)&Bs[((16 + qk) * 64 + lane) * 8];
      accA[qk] = __builtin_amdgcn_mfma_f32_16x16x32_bf16(af, bf, accA[qk], 0, 0, 0);
    }
    __syncthreads();
  }

  // epilogue: per-thread 32 slot-units (4 reg x 8 heads), identical op order to R3
  const int lp = l15, l = lp >> 2;
  const int wd = 64 >> l;
  const int st = (l == 0) ? 0 : (l == 1) ? 4096 : (l == 2) ? 5120 : 5376;
  const float lw = (float)wd;
  const int src = (quad << 4) | (2 * (lp & 7));
  float boO[16], boA[8];
#pragma unroll
  for (int p = 0; p < 16; ++p) boO[p] = boff[p * 16 + l15];
#pragma unroll
  for (int qk = 0; qk < 8; ++qk) boA[qk] = battn[qk * 16 + l15];

#pragma unroll
  for (int reg = 0; reg < 4; ++reg) {
    int grow = row_base + wv * 16 + quad * 4 + reg;
    float rx = refp[(size_t)grow * 8 + l * 2];
    float ry = refp[(size_t)grow * 8 + l * 2 + 1];
#pragma unroll
    for (int h = 0; h < 8; ++h) {
      float xa = accA[h][reg] + boA[h];
      float m = xa;
      m = fmaxf(m, __shfl_xor(m, 1, 64));
      m = fmaxf(m, __shfl_xor(m, 2, 64));
      m = fmaxf(m, __shfl_xor(m, 4, 64));
      m = fmaxf(m, __shfl_xor(m, 8, 64));
      float e = __expf(xa - m);
      float ssum = e;
      ssum += __shfl_xor(ssum, 1, 64);
      ssum += __shfl_xor(ssum, 2, 64);
      ssum += __shfl_xor(ssum, 4, 64);
      ssum += __shfl_xor(ssum, 8, 64);
      float aw = e / ssum;
      float v0 = accO[2 * h][reg] + boO[2 * h];
      float v1 = accO[2 * h + 1][reg] + boO[2 * h + 1];
      float x_lo = __shfl(v0, src, 64),     x_hi = __shfl(v1, src, 64);
      float y_lo = __shfl(v0, src | 1, 64), y_hi = __shfl(v1, src | 1, 64);
      float xo = (lp < 8) ? x_lo : x_hi;
      float yo = (lp < 8) ? y_lo : y_hi;
      float X = rx * lw + xo - 0.5f;     // == (ref + off/W)*W - 0.5
      float Y = ry * lw + yo - 0.5f;
      float fx = floorf(X), fy = floorf(Y);
      float lx = X - fx, ly = Y - fy;
      int x0 = (int)fx, y0 = (int)fy, x1 = x0 + 1, y1 = y0 + 1;
      int cx0 = min(max(x0, 0), wd - 1), cx1 = min(max(x1, 0), wd - 1);
      int cy0 = min(max(y0, 0), wd - 1), cy1 = min(max(y1, 0), wd - 1);
      float vx0 = (x0 >= 0 && x0 < wd) ? 1.f : 0.f;
      float vx1 = (x1 >= 0 && x1 < wd) ? 1.f : 0.f;
      float vy0 = (y0 >= 0 && y0 < wd) ? 1.f : 0.f;
      float vy1 = (y1 >= 0 && y1 < wd) ? 1.f : 0.f;
      float g00 = (1.f - lx) * (1.f - ly) * vx0 * vy0 * aw;
      float g01 = lx * (1.f - ly) * vx1 * vy0 * aw;
      float g10 = (1.f - lx) * ly * vx0 * vy1 * aw;
      float g11 = lx * ly * vx1 * vy1 * aw;
      uint i00 = st + cy0 * wd + cx0, i01 = st + cy0 * wd + cx1;
      uint i10 = st + cy1 * wd + cx0, i11 = st + cy1 * wd + cx1;
      uint4 ov;
      ov.x = i00 | (i01 << 16);
      ov.y = i10 | (i11 << 16);
      ov.z = (uint)f2b(g00) | ((uint)f2b(g01) << 16);
      ov.w = (uint)f2b(g10) | ((uint)f2b(g11) << 16);
      tblq[((size_t)grow * 8 + h) * 16 + lp] = ov;
    }
  }
}

// ---------------- K3: bilinear core, 2 rows per wave (round-0 best: 120.8us) ------
__global__ __launch_bounds__(512) void core_kernel(
    const ushort* __restrict__ value16, const uint4* __restrict__ tblq,
    uint* __restrict__ coreo32) {
  const int bx = blockIdx.x;           // 21760
  const int b = bx & 7;                // XCD-affine batch slice
  const int pr = bx >> 3;              // 0..2719
  const int brow0 = b * LQ + pr * 2;
  const int t = threadIdx.x;
  const int h = t >> 6, lane = t & 63;
  const int s = lane >> 3, g = lane & 7;
  const size_t sb = ((size_t)brow0 * 8 + h) * 16;
  uint4 sA0 = tblq[sb + s];
  uint4 sA1 = tblq[sb + 8 + s];
  uint4 sB0 = tblq[sb + 128 + s];
  uint4 sB1 = tblq[sb + 136 + s];
  const uint2* vb = (const uint2*)value16 + (size_t)b * (LQ * 64) + h * 8 + g;
  float a[4] = {0.f, 0.f, 0.f, 0.f};
  float c[4] = {0.f, 0.f, 0.f, 0.f};

  auto proc = [&](const uint4& sl, float* ac) {
    uint2 v00 = vb[(size_t)(sl.x & 0xFFFFu) * 64];
    uint2 v01 = vb[(size_t)(sl.x >> 16) * 64];
    uint2 v10 = vb[(size_t)(sl.y & 0xFFFFu) * 64];
    uint2 v11 = vb[(size_t)(sl.y >> 16) * 64];
    float w00 = blo(sl.z), w01 = bhi(sl.z), w10 = blo(sl.w), w11 = bhi(sl.w);
    ac[0] = fmaf(w00, blo(v00.x), ac[0]); ac[1] = fmaf(w00, bhi(v00.x), ac[1]);
    ac[2] = fmaf(w00, blo(v00.y), ac[2]); ac[3] = fmaf(w00, bhi(v00.y), ac[3]);
    ac[0] = fmaf(w01, blo(v01.x), ac[0]); ac[1] = fmaf(w01, bhi(v01.x), ac[1]);
    ac[2] = fmaf(w01, blo(v01.y), ac[2]); ac[3] = fmaf(w01, bhi(v01.y), ac[3]);
    ac[0] = fmaf(w10, blo(v10.x), ac[0]); ac[1] = fmaf(w10, bhi(v10.x), ac[1]);
    ac[2] = fmaf(w10, blo(v10.y), ac[2]); ac[3] = fmaf(w10, bhi(v10.y), ac[3]);
    ac[0] = fmaf(w11, blo(v11.x), ac[0]); ac[1] = fmaf(w11, bhi(v11.x), ac[1]);
    ac[2] = fmaf(w11, blo(v11.y), ac[2]); ac[3] = fmaf(w11, bhi(v11.y), ac[3]);
  };
  proc(sA0, a); proc(sA1, a);
  proc(sB0, c); proc(sB1, c);

#pragma unroll
  for (int m = 8; m <= 32; m <<= 1) {
#pragma unroll
    for (int i = 0; i < 4; ++i) {
      a[i] += __shfl_xor(a[i], m, 64);
      c[i] += __shfl_xor(c[i], m, 64);
    }
  }
  if (s == 0) {
    uint2 o0, o1;
    o0.x = (uint)f2b(a[0]) | ((uint)f2b(a[1]) << 16);
    o0.y = (uint)f2b(a[2]) | ((uint)f2b(a[3]) << 16);
    o1.x = (uint)f2b(c[0]) | ((uint)f2b(c[1]) << 16);
    o1.y = (uint)f2b(c[2]) | ((uint)f2b(c[3]) << 16);
    *(uint2*)(coreo32 + (size_t)brow0 * 128 + h * 16 + g * 2) = o0;
    *(uint2*)(coreo32 + (size_t)(brow0 + 1) * 128 + h * 16 + g * 2) = o1;
  }
}

// ---------------- K4: out GEMM, 64x256 full-N tile, A+B via global_load_lds --------
__global__ __launch_bounds__(256) void gemm_out64(
    const ushort* __restrict__ C, const ushort* __restrict__ WtU,
    const float* __restrict__ bout, float* __restrict__ out) {
  __shared__ ushort At[2048];
  __shared__ ushort Bs[8192];
  const int t = threadIdx.x, lane = t & 63, wv = t >> 6;
  const int row_base = blockIdx.x * 64;
  floatx4 acc[4][4];
#pragma unroll
  for (int i = 0; i < 4; ++i)
#pragma unroll
    for (int j = 0; j < 4; ++j) acc[i][j] = floatx4{0.f, 0.f, 0.f, 0.f};

  const ushort* asrc;
  {
    int mt = t >> 6, qq = (t >> 4) & 3, r15 = t & 15;
    asrc = C + (size_t)(row_base + mt * 16 + r15) * 256 + qq * 8;
  }
  const ushort* bsrc[4];
#pragma unroll
  for (int i = 0; i < 4; ++i) {
    int l = t + 256 * i;
    int nt = l >> 6, qq = (l >> 4) & 3, n15 = l & 15;
    bsrc[i] = WtU + (size_t)(nt * 16 + n15) * 256 + qq * 8;
  }

  for (int k0 = 0; k0 < 256; k0 += 32) {
    glds16(asrc + k0, &At[t * 8]);
#pragma unroll
    for (int i = 0; i < 4; ++i) glds16(bsrc[i] + k0, &Bs[(t + 256 * i) * 8]);
    __syncthreads();
    bf16x8 af[4], bf[4];
#pragma unroll
    for (int ti = 0; ti < 4; ++ti)
      af[ti] = *(const bf16x8*)&At[(ti * 64 + lane) * 8];
#pragma unroll
    for (int tj = 0; tj < 4; ++tj)
      bf[tj] = *(const bf16x8*)&Bs[((4 * wv + tj) * 64 + lane) * 8];
#pragma unroll
    for (int ti = 0; ti < 4; ++ti)
#pragma unroll
      for (int tj = 0; tj < 4; ++tj)
        acc[ti][tj] = __builtin_amdgcn_mfma_f32_16x16x32_bf16(af[ti], bf[tj], acc[ti][tj], 0, 0, 0);
    __syncthreads();
  }
  const int quad = lane >> 4, l15 = lane & 15;
#pragma unroll
  for (int tj = 0; tj < 4; ++tj) {
    int gcol = (4 * wv + tj) * 16 + l15;
    float b = bout[gcol];
#pragma unroll
    for (int ti = 0; ti < 4; ++ti)
#pragma unroll
      for (int reg = 0; reg < 4; ++reg) {
        int grow = row_base + ti * 16 + quad * 4 + reg;
        out[(size_t)grow * 256 + gcol] = acc[ti][tj][reg] + b;
      }
  }
}

extern "C" void kernel_launch(void* const* d_in, const int* in_sizes, int n_in,
                              void* d_out, int out_size, void* d_ws, size_t ws_size,
                              hipStream_t stream) {
  const float* query  = (const float*)d_in[0];
  const float* refp   = (const float*)d_in[1];
  const float* inpf   = (const float*)d_in[2];
  const float* W_val  = (const float*)d_in[5];
  const float* b_val  = (const float*)d_in[6];
  const float* W_off  = (const float*)d_in[7];
  const float* b_off  = (const float*)d_in[8];
  const float* W_attn = (const float*)d_in[9];
  const float* b_attn = (const float*)d_in[10];
  const float* W_out  = (const float*)d_in[11];
  const float* b_out  = (const float*)d_in[12];

  char* ws = (char*)d_ws;
  ushort* Wt    = (ushort*)ws;                        // 458,752 B used (1 MB reserved)
  ushort* value = (ushort*)(ws + 1048576);            // 22,282,240 B (bf16, row-major)
  uint4*  tbl   = (uint4*)(ws + 23330816);            // 89,128,960 B (16 B slots)
  ushort* coreo = (ushort*)(ws + 112459776);          // 22,282,240 B (bf16)
  // peak = 134,742,016 B

  dim3 blk(256);
  wcast_kernel<<<dim3(256, 4), blk, 0, stream>>>(W_val, W_off, W_attn, W_out, Wt);
  gemm_val64  <<<dim3(680), blk, 0, stream>>>(inpf, Wt, b_val, value);
  gemm_oa_kernel<<<dim3(680), blk, 0, stream>>>(query, Wt + 65536, b_off, b_attn, refp, tbl);
  core_kernel <<<dim3(21760), dim3(512), 0, stream>>>(value, tbl, (uint*)coreo);
  gemm_out64  <<<dim3(680), blk, 0, stream>>>(coreo, Wt + 163840, b_out, (float*)d_out);
}

// Round 10
// 337.891 us; speedup vs baseline: 1.0566x; 1.0351x over previous
//
#include <hip/hip_runtime.h>

typedef unsigned short ushort;
typedef unsigned int uint;
typedef __bf16 bf16x8 __attribute__((ext_vector_type(8)));
typedef float floatx4 __attribute__((ext_vector_type(4)));
typedef ushort ushort8 __attribute__((ext_vector_type(8)));

constexpr int LQ = 5440;
constexpr int ROWS = 43520;   // batch(8) * 5440

__device__ __forceinline__ ushort f2b(float f) {
  union { float f; uint i; } v; v.f = f;
  uint r = v.i + 0x7FFFu + ((v.i >> 16) & 1u);
  return (ushort)(r >> 16);
}
__device__ __forceinline__ float blo(uint u) {
  union { uint i; float f; } v; v.i = u << 16; return v.f;
}
__device__ __forceinline__ float bhi(uint u) {
  union { uint i; float f; } v; v.i = u & 0xFFFF0000u; return v.f;
}

// ---------------- weight transpose + cast: Wt[n][k] bf16 ----------------
// layout: [0]=Wval(256r) [65536]=Woff(256r)+Wattn(128r) fused 384-row block [163840]=Wout(256r)
__global__ __launch_bounds__(256) void wcast_kernel(
    const float* __restrict__ Wv, const float* __restrict__ Wo,
    const float* __restrict__ Wa, const float* __restrict__ Wu,
    ushort* __restrict__ Wt) {
  int k = threadIdx.x;    // 0..255
  int n = blockIdx.x;     // 0..255
  int m = blockIdx.y;     // 0..3
  const float* src = (m == 0) ? Wv : (m == 1) ? Wo : (m == 2) ? Wa : Wu;
  int N = (m == 2) ? 128 : 256;
  if (n >= N) return;
  size_t off = (size_t)m * 65536 - ((m == 3) ? 32768 : 0);  // 0,65536,131072,163840
  Wt[off + (size_t)n * 256 + k] = f2b(src[(size_t)k * N + n]);
}

// ---------------- 64x128 MFMA mainloop (K=256, BK=32), MFMA-order LDS ----------------
// Wave wv owns n-tiles {2wv, 2wv+1}, all 4 m-tiles. acc[ti][tjj].
template<bool F2B>
__device__ __forceinline__ void tile64_mainloop(
    const void* __restrict__ Av, const ushort* __restrict__ Bt,
    int row_base, int n0, ushort* At, ushort* Bs, floatx4 (&acc)[4][2]) {
  const int t = threadIdx.x;
  const int lane = t & 63, wv = t >> 6;
#pragma unroll
  for (int i = 0; i < 4; ++i)
#pragma unroll
    for (int j = 0; j < 2; ++j) acc[i][j] = floatx4{0.f, 0.f, 0.f, 0.f};

  for (int k0 = 0; k0 < 256; k0 += 32) {
    {
      int r = t >> 2, q = t & 3;       // 256 A-chunks, 1/thread
      int slot = ((r >> 4) * 64 + q * 16 + (r & 15)) * 8;
      if (F2B) {
        const float* ap = (const float*)Av + (size_t)(row_base + r) * 256 + k0 + q * 8;
        float4 a0 = *(const float4*)ap, a1 = *(const float4*)(ap + 4);
        ushort8 u;
        u[0] = f2b(a0.x); u[1] = f2b(a0.y); u[2] = f2b(a0.z); u[3] = f2b(a0.w);
        u[4] = f2b(a1.x); u[5] = f2b(a1.y); u[6] = f2b(a1.z); u[7] = f2b(a1.w);
        *(ushort8*)&At[slot] = u;
      } else {
        const ushort* ap = (const ushort*)Av + (size_t)(row_base + r) * 256 + k0 + q * 8;
        *(ushort8*)&At[slot] = *(const ushort8*)ap;
      }
    }
#pragma unroll
    for (int i = 0; i < 2; ++i) {      // 512 B-chunks, 2/thread
      int item = t + 256 * i;
      int nr = item >> 2, q = item & 3;
      int slot = ((nr >> 4) * 64 + q * 16 + (nr & 15)) * 8;
      *(ushort8*)&Bs[slot] = *(const ushort8*)(Bt + (size_t)(n0 + nr) * 256 + k0 + q * 8);
    }
    __syncthreads();
    bf16x8 af[4], bf[2];
#pragma unroll
    for (int ti = 0; ti < 4; ++ti)
      af[ti] = *(const bf16x8*)&At[(ti * 64 + lane) * 8];
#pragma unroll
    for (int tjj = 0; tjj < 2; ++tjj)
      bf[tjj] = *(const bf16x8*)&Bs[((2 * wv + tjj) * 64 + lane) * 8];
#pragma unroll
    for (int ti = 0; ti < 4; ++ti)
#pragma unroll
      for (int tjj = 0; tjj < 2; ++tjj)
        acc[ti][tjj] = __builtin_amdgcn_mfma_f32_16x16x32_bf16(af[ti], bf[tjj], acc[ti][tjj], 0, 0, 0);
    __syncthreads();
  }
}

// ---------------- K1: value GEMM (fp32 A, f2b in staging) -> bf16 value ----------------
__global__ __launch_bounds__(256) void gemm_val64(
    const float* __restrict__ X, const ushort* __restrict__ WtV,
    const float* __restrict__ bval, ushort* __restrict__ value16) {
  __shared__ ushort At[2048];
  __shared__ ushort Bs[4096];
  floatx4 acc[4][2];
  int row_base = blockIdx.x * 64, n0 = blockIdx.y * 128;
  tile64_mainloop<true>(X, WtV, row_base, n0, At, Bs, acc);
  const int t = threadIdx.x, lane = t & 63, wv = t >> 6;
  const int quad = lane >> 4, l15 = lane & 15;
#pragma unroll
  for (int tjj = 0; tjj < 2; ++tjj) {
    int gcol = n0 + (2 * wv + tjj) * 16 + l15;
    float b = bval[gcol];
#pragma unroll
    for (int ti = 0; ti < 4; ++ti)
#pragma unroll
      for (int reg = 0; reg < 4; ++reg) {
        int grow = row_base + ti * 16 + quad * 4 + reg;
        value16[(size_t)grow * 256 + gcol] = f2b(acc[ti][tjj][reg] + b);
      }
  }
}

// ---------------- K2: off+attn GEMM, head-pair sliced + softmax + slot finalize ----------------
__global__ __launch_bounds__(256) void gemm_oa_kernel(
    const float* __restrict__ Q, const ushort* __restrict__ WtOA,
    const float* __restrict__ boff, const float* __restrict__ battn,
    const float* __restrict__ refp, uint4* __restrict__ tblq) {
  __shared__ ushort At[2048];
  __shared__ ushort Bs[3072];
  const int t = threadIdx.x;
  const int lane = t & 63, wv = t >> 6;
  const int quad = lane >> 4, l15 = lane & 15;
  const int bx = blockIdx.x;
  const int row_base = (bx % 680) * 64;
  const int hp = bx / 680;            // 0..3
  floatx4 accO[4], accA[2];
#pragma unroll
  for (int p = 0; p < 4; ++p) accO[p] = floatx4{0.f, 0.f, 0.f, 0.f};
#pragma unroll
  for (int q = 0; q < 2; ++q) accA[q] = floatx4{0.f, 0.f, 0.f, 0.f};

  for (int k0 = 0; k0 < 256; k0 += 32) {
    {
      int r = t >> 2, q = t & 3;      // 256 A-chunks
      const float* ap = Q + (size_t)(row_base + r) * 256 + k0 + q * 8;
      float4 a0 = *(const float4*)ap, a1 = *(const float4*)(ap + 4);
      ushort8 u;
      u[0] = f2b(a0.x); u[1] = f2b(a0.y); u[2] = f2b(a0.z); u[3] = f2b(a0.w);
      u[4] = f2b(a1.x); u[5] = f2b(a1.y); u[6] = f2b(a1.z); u[7] = f2b(a1.w);
      *(ushort8*)&At[((r >> 4) * 64 + q * 16 + (r & 15)) * 8] = u;
    }
#pragma unroll
    for (int i = 0; i < 2; ++i) {     // 384 B-chunks
      int item = t + 256 * i;
      if (item < 384) {
        int nrl = item >> 2, q = item & 3;
        int grow_ = (nrl < 64) ? (hp * 64 + nrl) : (256 + hp * 32 + (nrl - 64));
        *(ushort8*)&Bs[((nrl >> 4) * 64 + q * 16 + (nrl & 15)) * 8] =
            *(const ushort8*)(WtOA + (size_t)grow_ * 256 + k0 + q * 8);
      }
    }
    __syncthreads();
    bf16x8 af = *(const bf16x8*)&At[(wv * 64 + lane) * 8];
#pragma unroll
    for (int p = 0; p < 4; ++p) {
      bf16x8 bf = *(const bf16x8*)&Bs[(p * 64 + lane) * 8];
      accO[p] = __builtin_amdgcn_mfma_f32_16x16x32_bf16(af, bf, accO[p], 0, 0, 0);
    }
#pragma unroll
    for (int q = 0; q < 2; ++q) {
      bf16x8 bf = *(const bf16x8*)&Bs[((4 + q) * 64 + lane) * 8];
      accA[q] = __builtin_amdgcn_mfma_f32_16x16x32_bf16(af, bf, accA[q], 0, 0, 0);
    }
    __syncthreads();
  }

  // epilogue: per-thread 8 slot-units (4 reg x 2 heads)
  const int lp = l15, l = lp >> 2;
  const int wd = 64 >> l;
  const int st = (l == 0) ? 0 : (l == 1) ? 4096 : (l == 2) ? 5120 : 5376;
  const float lw = (float)wd;
  const int src = (quad << 4) | (2 * (lp & 7));
  float boO[4], boA[2];
#pragma unroll
  for (int p = 0; p < 4; ++p) boO[p] = boff[(4 * hp + p) * 16 + l15];
#pragma unroll
  for (int q = 0; q < 2; ++q) boA[q] = battn[(2 * hp + q) * 16 + l15];

#pragma unroll
  for (int reg = 0; reg < 4; ++reg) {
    int grow = row_base + wv * 16 + quad * 4 + reg;
    float rx = refp[(size_t)grow * 8 + l * 2];
    float ry = refp[(size_t)grow * 8 + l * 2 + 1];
#pragma unroll
    for (int hh = 0; hh < 2; ++hh) {
      int h = 2 * hp + hh;
      float xa = accA[hh][reg] + boA[hh];
      float m = xa;
      m = fmaxf(m, __shfl_xor(m, 1, 64));
      m = fmaxf(m, __shfl_xor(m, 2, 64));
      m = fmaxf(m, __shfl_xor(m, 4, 64));
      m = fmaxf(m, __shfl_xor(m, 8, 64));
      float e = __expf(xa - m);
      float ssum = e;
      ssum += __shfl_xor(ssum, 1, 64);
      ssum += __shfl_xor(ssum, 2, 64);
      ssum += __shfl_xor(ssum, 4, 64);
      ssum += __shfl_xor(ssum, 8, 64);
      float aw = e / ssum;
      float v0 = accO[2 * hh][reg] + boO[2 * hh];
      float v1 = accO[2 * hh + 1][reg] + boO[2 * hh + 1];
      float x_lo = __shfl(v0, src, 64),     x_hi = __shfl(v1, src, 64);
      float y_lo = __shfl(v0, src | 1, 64), y_hi = __shfl(v1, src | 1, 64);
      float xo = (lp < 8) ? x_lo : x_hi;
      float yo = (lp < 8) ? y_lo : y_hi;
      float X = rx * lw + xo - 0.5f;     // == (ref + off/W)*W - 0.5
      float Y = ry * lw + yo - 0.5f;
      float fx = floorf(X), fy = floorf(Y);
      float lx = X - fx, ly = Y - fy;
      int x0 = (int)fx, y0 = (int)fy, x1 = x0 + 1, y1 = y0 + 1;
      int cx0 = min(max(x0, 0), wd - 1), cx1 = min(max(x1, 0), wd - 1);
      int cy0 = min(max(y0, 0), wd - 1), cy1 = min(max(y1, 0), wd - 1);
      float vx0 = (x0 >= 0 && x0 < wd) ? 1.f : 0.f;
      float vx1 = (x1 >= 0 && x1 < wd) ? 1.f : 0.f;
      float vy0 = (y0 >= 0 && y0 < wd) ? 1.f : 0.f;
      float vy1 = (y1 >= 0 && y1 < wd) ? 1.f : 0.f;
      float g00 = (1.f - lx) * (1.f - ly) * vx0 * vy0 * aw;
      float g01 = lx * (1.f - ly) * vx1 * vy0 * aw;
      float g10 = (1.f - lx) * ly * vx0 * vy1 * aw;
      float g11 = lx * ly * vx1 * vy1 * aw;
      uint i00 = st + cy0 * wd + cx0, i01 = st + cy0 * wd + cx1;
      uint i10 = st + cy1 * wd + cx0, i11 = st + cy1 * wd + cx1;
      uint4 ov;
      ov.x = i00 | (i01 << 16);
      ov.y = i10 | (i11 << 16);
      ov.z = (uint)f2b(g00) | ((uint)f2b(g01) << 16);
      ov.w = (uint)f2b(g10) | ((uint)f2b(g11) << 16);
      tblq[((size_t)grow * 8 + h) * 16 + lp] = ov;
    }
  }
}

// ---------------- K3: bilinear core (round-0 body), 3-way range split ----------------
// Split is a MEASUREMENT: each third ~40us, so any other dispatch >44us must
// surface in the rocprof top-5 table (previously hidden below core's 120us).
__global__ __launch_bounds__(512) void core_kernel(
    const ushort* __restrict__ value16, const uint4* __restrict__ tblq,
    uint* __restrict__ coreo32, int pr0) {
  const int bx = blockIdx.x;
  const int b = bx & 7;                // XCD-affine batch slice
  const int pr = (bx >> 3) + pr0;      // row-pair index 0..2719
  const int brow0 = b * LQ + pr * 2;
  const int t = threadIdx.x;
  const int h = t >> 6, lane = t & 63;
  const int s = lane >> 3, g = lane & 7;
  const size_t sb = ((size_t)brow0 * 8 + h) * 16;
  uint4 sA0 = tblq[sb + s];
  uint4 sA1 = tblq[sb + 8 + s];
  uint4 sB0 = tblq[sb + 128 + s];
  uint4 sB1 = tblq[sb + 136 + s];
  const uint2* vb = (const uint2*)value16 + (size_t)b * (LQ * 64) + h * 8 + g;
  float a[4] = {0.f, 0.f, 0.f, 0.f};
  float c[4] = {0.f, 0.f, 0.f, 0.f};

  auto proc = [&](const uint4& sl, float* ac) {
    uint2 v00 = vb[(size_t)(sl.x & 0xFFFFu) * 64];
    uint2 v01 = vb[(size_t)(sl.x >> 16) * 64];
    uint2 v10 = vb[(size_t)(sl.y & 0xFFFFu) * 64];
    uint2 v11 = vb[(size_t)(sl.y >> 16) * 64];
    float w00 = blo(sl.z), w01 = bhi(sl.z), w10 = blo(sl.w), w11 = bhi(sl.w);
    ac[0] = fmaf(w00, blo(v00.x), ac[0]); ac[1] = fmaf(w00, bhi(v00.x), ac[1]);
    ac[2] = fmaf(w00, blo(v00.y), ac[2]); ac[3] = fmaf(w00, bhi(v00.y), ac[3]);
    ac[0] = fmaf(w01, blo(v01.x), ac[0]); ac[1] = fmaf(w01, bhi(v01.x), ac[1]);
    ac[2] = fmaf(w01, blo(v01.y), ac[2]); ac[3] = fmaf(w01, bhi(v01.y), ac[3]);
    ac[0] = fmaf(w10, blo(v10.x), ac[0]); ac[1] = fmaf(w10, bhi(v10.x), ac[1]);
    ac[2] = fmaf(w10, blo(v10.y), ac[2]); ac[3] = fmaf(w10, bhi(v10.y), ac[3]);
    ac[0] = fmaf(w11, blo(v11.x), ac[0]); ac[1] = fmaf(w11, bhi(v11.x), ac[1]);
    ac[2] = fmaf(w11, blo(v11.y), ac[2]); ac[3] = fmaf(w11, bhi(v11.y), ac[3]);
  };
  proc(sA0, a); proc(sA1, a);
  proc(sB0, c); proc(sB1, c);

#pragma unroll
  for (int m = 8; m <= 32; m <<= 1) {
#pragma unroll
    for (int i = 0; i < 4; ++i) {
      a[i] += __shfl_xor(a[i], m, 64);
      c[i] += __shfl_xor(c[i], m, 64);
    }
  }
  if (s == 0) {
    uint2 o0, o1;
    o0.x = (uint)f2b(a[0]) | ((uint)f2b(a[1]) << 16);
    o0.y = (uint)f2b(a[2]) | ((uint)f2b(a[3]) << 16);
    o1.x = (uint)f2b(c[0]) | ((uint)f2b(c[1]) << 16);
    o1.y = (uint)f2b(c[2]) | ((uint)f2b(c[3]) << 16);
    *(uint2*)(coreo32 + (size_t)brow0 * 128 + h * 16 + g * 2) = o0;
    *(uint2*)(coreo32 + (size_t)(brow0 + 1) * 128 + h * 16 + g * 2) = o1;
  }
}

// ---------------- K4: out GEMM (A = core bf16) -> fp32 d_out ----------------
__global__ __launch_bounds__(256) void gemm_out64(
    const ushort* __restrict__ C, const ushort* __restrict__ WtU,
    const float* __restrict__ bout, float* __restrict__ out) {
  __shared__ ushort At[2048];
  __shared__ ushort Bs[4096];
  floatx4 acc[4][2];
  int row_base = blockIdx.x * 64, n0 = blockIdx.y * 128;
  tile64_mainloop<false>(C, WtU, row_base, n0, At, Bs, acc);
  const int t = threadIdx.x, lane = t & 63, wv = t >> 6;
  const int quad = lane >> 4, l15 = lane & 15;
#pragma unroll
  for (int tjj = 0; tjj < 2; ++tjj) {
    int gcol = n0 + (2 * wv + tjj) * 16 + l15;
    float b = bout[gcol];
#pragma unroll
    for (int ti = 0; ti < 4; ++ti)
#pragma unroll
      for (int reg = 0; reg < 4; ++reg) {
        int grow = row_base + ti * 16 + quad * 4 + reg;
        out[(size_t)grow * 256 + gcol] = acc[ti][tjj][reg] + b;
      }
  }
}

extern "C" void kernel_launch(void* const* d_in, const int* in_sizes, int n_in,
                              void* d_out, int out_size, void* d_ws, size_t ws_size,
                              hipStream_t stream) {
  const float* query  = (const float*)d_in[0];
  const float* refp   = (const float*)d_in[1];
  const float* inpf   = (const float*)d_in[2];
  const float* W_val  = (const float*)d_in[5];
  const float* b_val  = (const float*)d_in[6];
  const float* W_off  = (const float*)d_in[7];
  const float* b_off  = (const float*)d_in[8];
  const float* W_attn = (const float*)d_in[9];
  const float* b_attn = (const float*)d_in[10];
  const float* W_out  = (const float*)d_in[11];
  const float* b_out  = (const float*)d_in[12];

  char* ws = (char*)d_ws;
  ushort* Wt    = (ushort*)ws;                        // 458,752 B used (1 MB reserved)
  ushort* value = (ushort*)(ws + 1048576);            // 22,282,240 B (bf16)
  uint4*  tbl   = (uint4*)(ws + 23330816);            // 89,128,960 B (16 B slots)
  ushort* coreo = (ushort*)(ws + 112459776);          // 22,282,240 B (bf16)
  // peak = 134,742,016 B

  dim3 blk(256);
  wcast_kernel<<<dim3(256, 4), blk, 0, stream>>>(W_val, W_off, W_attn, W_out, Wt);
  gemm_val64  <<<dim3(680, 2), blk, 0, stream>>>(inpf, Wt, b_val, value);
  gemm_oa_kernel<<<dim3(2720), blk, 0, stream>>>(query, Wt + 65536, b_off, b_attn, refp, tbl);
  // core split into 3 range-dispatches (pr in [0,908) [908,1816) [1816,2720))
  core_kernel <<<dim3(8 * 908), dim3(512), 0, stream>>>(value, tbl, (uint*)coreo, 0);
  core_kernel <<<dim3(8 * 908), dim3(512), 0, stream>>>(value, tbl, (uint*)coreo, 908);
  core_kernel <<<dim3(8 * 904), dim3(512), 0, stream>>>(value, tbl, (uint*)coreo, 1816);
  gemm_out64  <<<dim3(680, 2), blk, 0, stream>>>(coreo, Wt + 163840, b_out, (float*)d_out);
}

// Round 11
// 333.509 us; speedup vs baseline: 1.0705x; 1.0131x over previous
//
#include <hip/hip_runtime.h>

typedef unsigned short ushort;
typedef unsigned int uint;
typedef __bf16 bf16x8 __attribute__((ext_vector_type(8)));
typedef float floatx4 __attribute__((ext_vector_type(4)));
typedef ushort ushort8 __attribute__((ext_vector_type(8)));

constexpr int LQ = 5440;
constexpr int ROWS = 43520;   // batch(8) * 5440

__device__ __forceinline__ ushort f2b(float f) {
  union { float f; uint i; } v; v.f = f;
  uint r = v.i + 0x7FFFu + ((v.i >> 16) & 1u);
  return (ushort)(r >> 16);
}
__device__ __forceinline__ float blo(uint u) {
  union { uint i; float f; } v; v.i = u << 16; return v.f;
}
__device__ __forceinline__ float bhi(uint u) {
  union { uint i; float f; } v; v.i = u & 0xFFFF0000u; return v.f;
}
// async global->LDS, 16B per lane; LDS dest must be uniform_base + lane*16
__device__ __forceinline__ void glds16(const ushort* g, ushort* l) {
  __builtin_amdgcn_global_load_lds(
      (const __attribute__((address_space(1))) void*)g,
      (__attribute__((address_space(3))) void*)l, 16, 0, 0);
}

// ---------------- weight transpose + cast: Wt[n][k] bf16 ----------------
// layout: [0]=Wval(256r) [65536]=Woff(256r)+Wattn(128r) fused 384-row block [163840]=Wout(256r)
__global__ __launch_bounds__(256) void wcast_kernel(
    const float* __restrict__ Wv, const float* __restrict__ Wo,
    const float* __restrict__ Wa, const float* __restrict__ Wu,
    ushort* __restrict__ Wt) {
  int k = threadIdx.x;    // 0..255
  int n = blockIdx.x;     // 0..255
  int m = blockIdx.y;     // 0..3
  const float* src = (m == 0) ? Wv : (m == 1) ? Wo : (m == 2) ? Wa : Wu;
  int N = (m == 2) ? 128 : 256;
  if (n >= N) return;
  size_t off = (size_t)m * 65536 - ((m == 3) ? 32768 : 0);  // 0,65536,131072,163840
  Wt[off + (size_t)n * 256 + k] = f2b(src[(size_t)k * N + n]);
}

// ---------------- 64x128 MFMA mainloop (K=256, BK=32), linear-slot staging -------
// Thread t writes LDS slot t (A) / slots {t,t+256} (B): chunk->thread assignment
// permuted so ds_write_b128 is sequential (0 bank conflicts); same address set
// per wave (coalescing unchanged), same final LDS contents as MFMA order.
template<bool F2B>
__device__ __forceinline__ void tile64_mainloop(
    const void* __restrict__ Av, const ushort* __restrict__ Bt,
    int row_base, int n0, ushort* At, ushort* Bs, floatx4 (&acc)[4][2]) {
  const int t = threadIdx.x;
  const int lane = t & 63, wv = t >> 6;
#pragma unroll
  for (int i = 0; i < 4; ++i)
#pragma unroll
    for (int j = 0; j < 2; ++j) acc[i][j] = floatx4{0.f, 0.f, 0.f, 0.f};

  const int arow = ((t >> 6) << 4) + (t & 15);
  const int akoff = ((t >> 4) & 3) * 8;
  const float* apf = (const float*)Av + (size_t)(row_base + arow) * 256 + akoff;
  const ushort* aph = (const ushort*)Av + (size_t)(row_base + arow) * 256 + akoff;
  const ushort* bp[2];
#pragma unroll
  for (int i = 0; i < 2; ++i) {
    int l = t + 256 * i;
    int nr = ((l >> 6) << 4) + (l & 15);
    int koff = ((l >> 4) & 3) * 8;
    bp[i] = Bt + (size_t)(n0 + nr) * 256 + koff;
  }

  for (int k0 = 0; k0 < 256; k0 += 32) {
    if (F2B) {
      float4 a0 = *(const float4*)(apf + k0), a1 = *(const float4*)(apf + k0 + 4);
      ushort8 u;
      u[0] = f2b(a0.x); u[1] = f2b(a0.y); u[2] = f2b(a0.z); u[3] = f2b(a0.w);
      u[4] = f2b(a1.x); u[5] = f2b(a1.y); u[6] = f2b(a1.z); u[7] = f2b(a1.w);
      *(ushort8*)&At[t * 8] = u;
    } else {
      *(ushort8*)&At[t * 8] = *(const ushort8*)(aph + k0);
    }
    *(ushort8*)&Bs[t * 8] = *(const ushort8*)(bp[0] + k0);
    *(ushort8*)&Bs[(t + 256) * 8] = *(const ushort8*)(bp[1] + k0);
    __syncthreads();
    bf16x8 af[4], bf[2];
#pragma unroll
    for (int ti = 0; ti < 4; ++ti)
      af[ti] = *(const bf16x8*)&At[(ti * 64 + lane) * 8];
#pragma unroll
    for (int tjj = 0; tjj < 2; ++tjj)
      bf[tjj] = *(const bf16x8*)&Bs[((2 * wv + tjj) * 64 + lane) * 8];
#pragma unroll
    for (int ti = 0; ti < 4; ++ti)
#pragma unroll
      for (int tjj = 0; tjj < 2; ++tjj)
        acc[ti][tjj] = __builtin_amdgcn_mfma_f32_16x16x32_bf16(af[ti], bf[tjj], acc[ti][tjj], 0, 0, 0);
    __syncthreads();
  }
}

// ---------------- K1: value GEMM (fp32 A, f2b in staging) -> bf16 value ----------------
__global__ __launch_bounds__(256) void gemm_val64(
    const float* __restrict__ X, const ushort* __restrict__ WtV,
    const float* __restrict__ bval, ushort* __restrict__ value16) {
  __shared__ ushort At[2048];
  __shared__ ushort Bs[4096];
  floatx4 acc[4][2];
  int row_base = blockIdx.x * 64, n0 = blockIdx.y * 128;
  tile64_mainloop<true>(X, WtV, row_base, n0, At, Bs, acc);
  const int t = threadIdx.x, lane = t & 63, wv = t >> 6;
  const int quad = lane >> 4, l15 = lane & 15;
#pragma unroll
  for (int tjj = 0; tjj < 2; ++tjj) {
    int gcol = n0 + (2 * wv + tjj) * 16 + l15;
    float b = bval[gcol];
#pragma unroll
    for (int ti = 0; ti < 4; ++ti)
#pragma unroll
      for (int reg = 0; reg < 4; ++reg) {
        int grow = row_base + ti * 16 + quad * 4 + reg;
        value16[(size_t)grow * 256 + gcol] = f2b(acc[ti][tjj][reg] + b);
      }
  }
}

// ---------------- K2: off+attn GEMM, A staged ONCE in LDS + hp loop ----------------
// 680 blocks x 64 rows. Phase 0: Q[64x256] -> bf16 LDS (8 panels, linear writes).
// Then hp=0..3: per k-step stage B (96r x 32k) via glds16 (L2-hot), 6 MFMA; epilogue.
// Q traffic /4 vs hp-sliced version; zero A-latency in main loop; acc stays [6].
__global__ __launch_bounds__(256) void gemm_oa_kernel(
    const float* __restrict__ Q, const ushort* __restrict__ WtOA,
    const float* __restrict__ boff, const float* __restrict__ battn,
    const float* __restrict__ refp, uint4* __restrict__ tblq) {
  __shared__ ushort At[16384];   // 8 panels x (64r x 32k), MFMA order
  __shared__ ushort Bs[3072];    // 96r x 32k, MFMA order (per hp, per k-step)
  const int t = threadIdx.x;
  const int lane = t & 63, wv = t >> 6;
  const int quad = lane >> 4, l15 = lane & 15;
  const int row_base = blockIdx.x * 64;

  // ---- phase 0: prestage A (linear-slot writes, zero conflicts) ----
  {
    int rowl = ((t >> 6) << 4) + (t & 15);
    int koff = ((t >> 4) & 3) * 8;
    const float* ap = Q + (size_t)(row_base + rowl) * 256 + koff;
#pragma unroll
    for (int p = 0; p < 8; ++p) {
      float4 a0 = *(const float4*)(ap + p * 32), a1 = *(const float4*)(ap + p * 32 + 4);
      ushort8 u;
      u[0] = f2b(a0.x); u[1] = f2b(a0.y); u[2] = f2b(a0.z); u[3] = f2b(a0.w);
      u[4] = f2b(a1.x); u[5] = f2b(a1.y); u[6] = f2b(a1.z); u[7] = f2b(a1.w);
      *(ushort8*)&At[p * 2048 + t * 8] = u;
    }
  }

  // B sources for hp=0 + per-hp row stride (chunk t and, for t<128, chunk t+256)
  const ushort* bsrc0;
  size_t bstr0;
  {
    int nr = ((t >> 6) << 4) + (t & 15);     // 0..63  (off region)
    int koff = ((t >> 4) & 3) * 8;
    bsrc0 = WtOA + (size_t)nr * 256 + koff;
    bstr0 = (size_t)64 * 256;
  }
  const ushort* bsrc1 = nullptr;
  size_t bstr1 = 0;
  if (t < 128) {
    int l = t + 256;                          // nr 64..95 (attn region)
    int nr = ((l >> 6) << 4) + (l & 15);
    int koff = ((l >> 4) & 3) * 8;
    bsrc1 = WtOA + (size_t)(256 + (nr - 64)) * 256 + koff;
    bstr1 = (size_t)32 * 256;
  }
  __syncthreads();

  const int lp = l15, lev = lp >> 2;
  const int wd = 64 >> lev;
  const int st = (lev == 0) ? 0 : (lev == 1) ? 4096 : (lev == 2) ? 5120 : 5376;
  const float lw = (float)wd;
  const int src = (quad << 4) | (2 * (lp & 7));
  float rxs[4], rys[4];
#pragma unroll
  for (int reg = 0; reg < 4; ++reg) {
    int grow = row_base + wv * 16 + quad * 4 + reg;
    rxs[reg] = refp[(size_t)grow * 8 + lev * 2];
    rys[reg] = refp[(size_t)grow * 8 + lev * 2 + 1];
  }

  for (int hp = 0; hp < 4; ++hp) {
    floatx4 accO[4], accA[2];
#pragma unroll
    for (int p = 0; p < 4; ++p) accO[p] = floatx4{0.f, 0.f, 0.f, 0.f};
#pragma unroll
    for (int q = 0; q < 2; ++q) accA[q] = floatx4{0.f, 0.f, 0.f, 0.f};

    const ushort* b0 = bsrc0 + (size_t)hp * bstr0;
    const ushort* b1 = (t < 128) ? (bsrc1 + (size_t)hp * bstr1) : nullptr;

    for (int p = 0; p < 8; ++p) {
      glds16(b0 + p * 32, &Bs[t * 8]);
      if (t < 128) glds16(b1 + p * 32, &Bs[(t + 256) * 8]);
      __syncthreads();
      bf16x8 af = *(const bf16x8*)&At[p * 2048 + (wv * 64 + lane) * 8];
#pragma unroll
      for (int pp = 0; pp < 4; ++pp) {
        bf16x8 bf = *(const bf16x8*)&Bs[(pp * 64 + lane) * 8];
        accO[pp] = __builtin_amdgcn_mfma_f32_16x16x32_bf16(af, bf, accO[pp], 0, 0, 0);
      }
#pragma unroll
      for (int qk = 0; qk < 2; ++qk) {
        bf16x8 bf = *(const bf16x8*)&Bs[((4 + qk) * 64 + lane) * 8];
        accA[qk] = __builtin_amdgcn_mfma_f32_16x16x32_bf16(af, bf, accA[qk], 0, 0, 0);
      }
      __syncthreads();
    }

    // epilogue for this hp: identical op order to round-0
    float boO[4], boA[2];
#pragma unroll
    for (int p = 0; p < 4; ++p) boO[p] = boff[(4 * hp + p) * 16 + l15];
#pragma unroll
    for (int q = 0; q < 2; ++q) boA[q] = battn[(2 * hp + q) * 16 + l15];

#pragma unroll
    for (int reg = 0; reg < 4; ++reg) {
      int grow = row_base + wv * 16 + quad * 4 + reg;
      float rx = rxs[reg];
      float ry = rys[reg];
#pragma unroll
      for (int hh = 0; hh < 2; ++hh) {
        int h = 2 * hp + hh;
        float xa = accA[hh][reg] + boA[hh];
        float m = xa;
        m = fmaxf(m, __shfl_xor(m, 1, 64));
        m = fmaxf(m, __shfl_xor(m, 2, 64));
        m = fmaxf(m, __shfl_xor(m, 4, 64));
        m = fmaxf(m, __shfl_xor(m, 8, 64));
        float e = __expf(xa - m);
        float ssum = e;
        ssum += __shfl_xor(ssum, 1, 64);
        ssum += __shfl_xor(ssum, 2, 64);
        ssum += __shfl_xor(ssum, 4, 64);
        ssum += __shfl_xor(ssum, 8, 64);
        float aw = e / ssum;
        float v0 = accO[2 * hh][reg] + boO[2 * hh];
        float v1 = accO[2 * hh + 1][reg] + boO[2 * hh + 1];
        float x_lo = __shfl(v0, src, 64),     x_hi = __shfl(v1, src, 64);
        float y_lo = __shfl(v0, src | 1, 64), y_hi = __shfl(v1, src | 1, 64);
        float xo = (lp < 8) ? x_lo : x_hi;
        float yo = (lp < 8) ? y_lo : y_hi;
        float X = rx * lw + xo - 0.5f;     // == (ref + off/W)*W - 0.5
        float Y = ry * lw + yo - 0.5f;
        float fx = floorf(X), fy = floorf(Y);
        float lx = X - fx, ly = Y - fy;
        int x0 = (int)fx, y0 = (int)fy, x1 = x0 + 1, y1 = y0 + 1;
        int cx0 = min(max(x0, 0), wd - 1), cx1 = min(max(x1, 0), wd - 1);
        int cy0 = min(max(y0, 0), wd - 1), cy1 = min(max(y1, 0), wd - 1);
        float vx0 = (x0 >= 0 && x0 < wd) ? 1.f : 0.f;
        float vx1 = (x1 >= 0 && x1 < wd) ? 1.f : 0.f;
        float vy0 = (y0 >= 0 && y0 < wd) ? 1.f : 0.f;
        float vy1 = (y1 >= 0 && y1 < wd) ? 1.f : 0.f;
        float g00 = (1.f - lx) * (1.f - ly) * vx0 * vy0 * aw;
        float g01 = lx * (1.f - ly) * vx1 * vy0 * aw;
        float g10 = (1.f - lx) * ly * vx0 * vy1 * aw;
        float g11 = lx * ly * vx1 * vy1 * aw;
        uint i00 = st + cy0 * wd + cx0, i01 = st + cy0 * wd + cx1;
        uint i10 = st + cy1 * wd + cx0, i11 = st + cy1 * wd + cx1;
        uint4 ov;
        ov.x = i00 | (i01 << 16);
        ov.y = i10 | (i11 << 16);
        ov.z = (uint)f2b(g00) | ((uint)f2b(g01) << 16);
        ov.w = (uint)f2b(g10) | ((uint)f2b(g11) << 16);
        tblq[((size_t)grow * 8 + h) * 16 + lp] = ov;
      }
    }
  }
}

// ---------------- K3: bilinear core, 2 rows per wave (round-0 best: 120.8us) ------
__global__ __launch_bounds__(512) void core_kernel(
    const ushort* __restrict__ value16, const uint4* __restrict__ tblq,
    uint* __restrict__ coreo32) {
  const int bx = blockIdx.x;           // 21760
  const int b = bx & 7;                // XCD-affine batch slice
  const int pr = bx >> 3;              // 0..2719
  const int brow0 = b * LQ + pr * 2;
  const int t = threadIdx.x;
  const int h = t >> 6, lane = t & 63;
  const int s = lane >> 3, g = lane & 7;
  const size_t sb = ((size_t)brow0 * 8 + h) * 16;
  uint4 sA0 = tblq[sb + s];
  uint4 sA1 = tblq[sb + 8 + s];
  uint4 sB0 = tblq[sb + 128 + s];
  uint4 sB1 = tblq[sb + 136 + s];
  const uint2* vb = (const uint2*)value16 + (size_t)b * (LQ * 64) + h * 8 + g;
  float a[4] = {0.f, 0.f, 0.f, 0.f};
  float c[4] = {0.f, 0.f, 0.f, 0.f};

  auto proc = [&](const uint4& sl, float* ac) {
    uint2 v00 = vb[(size_t)(sl.x & 0xFFFFu) * 64];
    uint2 v01 = vb[(size_t)(sl.x >> 16) * 64];
    uint2 v10 = vb[(size_t)(sl.y & 0xFFFFu) * 64];
    uint2 v11 = vb[(size_t)(sl.y >> 16) * 64];
    float w00 = blo(sl.z), w01 = bhi(sl.z), w10 = blo(sl.w), w11 = bhi(sl.w);
    ac[0] = fmaf(w00, blo(v00.x), ac[0]); ac[1] = fmaf(w00, bhi(v00.x), ac[1]);
    ac[2] = fmaf(w00, blo(v00.y), ac[2]); ac[3] = fmaf(w00, bhi(v00.y), ac[3]);
    ac[0] = fmaf(w01, blo(v01.x), ac[0]); ac[1] = fmaf(w01, bhi(v01.x), ac[1]);
    ac[2] = fmaf(w01, blo(v01.y), ac[2]); ac[3] = fmaf(w01, bhi(v01.y), ac[3]);
    ac[0] = fmaf(w10, blo(v10.x), ac[0]); ac[1] = fmaf(w10, bhi(v10.x), ac[1]);
    ac[2] = fmaf(w10, blo(v10.y), ac[2]); ac[3] = fmaf(w10, bhi(v10.y), ac[3]);
    ac[0] = fmaf(w11, blo(v11.x), ac[0]); ac[1] = fmaf(w11, bhi(v11.x), ac[1]);
    ac[2] = fmaf(w11, blo(v11.y), ac[2]); ac[3] = fmaf(w11, bhi(v11.y), ac[3]);
  };
  proc(sA0, a); proc(sA1, a);
  proc(sB0, c); proc(sB1, c);

#pragma unroll
  for (int m = 8; m <= 32; m <<= 1) {
#pragma unroll
    for (int i = 0; i < 4; ++i) {
      a[i] += __shfl_xor(a[i], m, 64);
      c[i] += __shfl_xor(c[i], m, 64);
    }
  }
  if (s == 0) {
    uint2 o0, o1;
    o0.x = (uint)f2b(a[0]) | ((uint)f2b(a[1]) << 16);
    o0.y = (uint)f2b(a[2]) | ((uint)f2b(a[3]) << 16);
    o1.x = (uint)f2b(c[0]) | ((uint)f2b(c[1]) << 16);
    o1.y = (uint)f2b(c[2]) | ((uint)f2b(c[3]) << 16);
    *(uint2*)(coreo32 + (size_t)brow0 * 128 + h * 16 + g * 2) = o0;
    *(uint2*)(coreo32 + (size_t)(brow0 + 1) * 128 + h * 16 + g * 2) = o1;
  }
}

// ---------------- K4: out GEMM (A = core bf16) -> fp32 d_out ----------------
__global__ __launch_bounds__(256) void gemm_out64(
    const ushort* __restrict__ C, const ushort* __restrict__ WtU,
    const float* __restrict__ bout, float* __restrict__ out) {
  __shared__ ushort At[2048];
  __shared__ ushort Bs[4096];
  floatx4 acc[4][2];
  int row_base = blockIdx.x * 64, n0 = blockIdx.y * 128;
  tile64_mainloop<false>(C, WtU, row_base, n0, At, Bs, acc);
  const int t = threadIdx.x, lane = t & 63, wv = t >> 6;
  const int quad = lane >> 4, l15 = lane & 15;
#pragma unroll
  for (int tjj = 0; tjj < 2; ++tjj) {
    int gcol = n0 + (2 * wv + tjj) * 16 + l15;
    float b = bout[gcol];
#pragma unroll
    for (int ti = 0; ti < 4; ++ti)
#pragma unroll
      for (int reg = 0; reg < 4; ++reg) {
        int grow = row_base + ti * 16 + quad * 4 + reg;
        out[(size_t)grow * 256 + gcol] = acc[ti][tjj][reg] + b;
      }
  }
}

extern "C" void kernel_launch(void* const* d_in, const int* in_sizes, int n_in,
                              void* d_out, int out_size, void* d_ws, size_t ws_size,
                              hipStream_t stream) {
  const float* query  = (const float*)d_in[0];
  const float* refp   = (const float*)d_in[1];
  const float* inpf   = (const float*)d_in[2];
  const float* W_val  = (const float*)d_in[5];
  const float* b_val  = (const float*)d_in[6];
  const float* W_off  = (const float*)d_in[7];
  const float* b_off  = (const float*)d_in[8];
  const float* W_attn = (const float*)d_in[9];
  const float* b_attn = (const float*)d_in[10];
  const float* W_out  = (const float*)d_in[11];
  const float* b_out  = (const float*)d_in[12];

  char* ws = (char*)d_ws;
  ushort* Wt    = (ushort*)ws;                        // 458,752 B used (1 MB reserved)
  ushort* value = (ushort*)(ws + 1048576);            // 22,282,240 B (bf16)
  uint4*  tbl   = (uint4*)(ws + 23330816);            // 89,128,960 B (16 B slots)
  ushort* coreo = (ushort*)(ws + 112459776);          // 22,282,240 B (bf16)
  // peak = 134,742,016 B

  dim3 blk(256);
  wcast_kernel<<<dim3(256, 4), blk, 0, stream>>>(W_val, W_off, W_attn, W_out, Wt);
  gemm_val64  <<<dim3(680, 2), blk, 0, stream>>>(inpf, Wt, b_val, value);
  gemm_oa_kernel<<<dim3(680), blk, 0, stream>>>(query, Wt + 65536, b_off, b_attn, refp, tbl);
  core_kernel <<<dim3(21760), dim3(512), 0, stream>>>(value, tbl, (uint*)coreo);
  gemm_out64  <<<dim3(680, 2), blk, 0, stream>>>(coreo, Wt + 163840, b_out, (float*)d_out);
}